// Round 4
// baseline (469.129 us; speedup 1.0000x reference)
//
#include <hip/hip_runtime.h>
#include <hip/hip_bf16.h>

#define HDIM 128
#define CDIM 8

// Harness contract (pinned empirically, rounds 1-3):
//   float32 tensors  -> const float*  (R2: reading as bf16 gave NaN = fp32 bits as bf16)
//   int64 edge_index -> const int*    (R1: reading as int64 overran 6.4MB buffer -> fault)
//   output (float32) -> float*        (R3: writing bf16 gave absmax ~= max|ref|, the
//                                      packed-bf16-decoded-as-fp32 signature)

// ---------- CSR build ----------
__global__ void k_zero_int(int* __restrict__ p, int n) {
    int i = blockIdx.x * blockDim.x + threadIdx.x;
    if (i < n) p[i] = 0;
}

__global__ void k_hist(const int* __restrict__ col, int* __restrict__ cnt, int E) {
    int e = blockIdx.x * blockDim.x + threadIdx.x;
    if (e < E) atomicAdd(&cnt[col[e]], 1);
}

// single-block exclusive scan over cnt[0..n) -> ptr, cursor; also dinv = rsqrt(cnt+1)
__global__ __launch_bounds__(1024) void k_scan(const int* __restrict__ cnt,
                                               int* __restrict__ ptr,
                                               int* __restrict__ cursor,
                                               float* __restrict__ dinv, int n) {
    __shared__ int sh[1024];
    __shared__ int carry_sh;
    int tid = threadIdx.x;
    if (tid == 0) carry_sh = 0;
    __syncthreads();
    for (int base = 0; base < n; base += 1024) {
        int i = base + tid;
        int v = (i < n) ? cnt[i] : 0;
        sh[tid] = v;
        __syncthreads();
        for (int off = 1; off < 1024; off <<= 1) {
            int t = (tid >= off) ? sh[tid - off] : 0;
            __syncthreads();
            sh[tid] += t;
            __syncthreads();
        }
        int carry = carry_sh;
        if (i < n) {
            int excl = carry + sh[tid] - v;
            ptr[i] = excl;
            cursor[i] = excl;
            dinv[i] = rsqrtf((float)v + 1.0f);   // +1 self-loop; always > 0
        }
        int tsum = sh[1023];
        __syncthreads();
        if (tid == 0) carry_sh = carry + tsum;
        __syncthreads();
    }
    if (tid == 0) ptr[n] = carry_sh;
}

__global__ void k_scatter(const int* __restrict__ ei, int* __restrict__ cursor,
                          int* __restrict__ srcIdx, int E) {
    int e = blockIdx.x * blockDim.x + threadIdx.x;
    if (e < E) {
        int c = ei[(size_t)E + e];   // target (col)
        int r = ei[e];               // source (row)
        int pos = atomicAdd(&cursor[c], 1);
        srcIdx[pos] = r;
    }
}

// ---------- dense GEMM: Y[n,128] = X[n,128] @ W[128,128], fp32 ----------
// 256 threads = 2 row-groups x 128 cols; 32 rows/block; x tile in LDS (16 KB,
// broadcast float4 reads); W streamed from global (64 KB, L1/L2 resident,
// 16 FMA per scalar W load).
__global__ __launch_bounds__(256) void k_gemm(const float* __restrict__ X,
                                              const float* __restrict__ W,
                                              float* __restrict__ Y, int nrows) {
    __shared__ float xsh[32][HDIM];
    int tid = threadIdx.x;
    int c = tid & 127;         // output column
    int g = tid >> 7;          // row-group: 0 or 1
    int r0 = blockIdx.x * 32;

    // stage 32 rows of X (zero-fill past nrows)
    for (int idx = tid; idx < 32 * HDIM / 4; idx += 256) {
        int row = idx >> 5;            // idx / 32
        int kk = (idx & 31) * 4;
        int gr = r0 + row;
        float4 v = make_float4(0.f, 0.f, 0.f, 0.f);
        if (gr < nrows) v = *(const float4*)(X + (size_t)gr * HDIM + kk);
        *(float4*)&xsh[row][kk] = v;
    }
    __syncthreads();

    float acc[16];
#pragma unroll
    for (int r = 0; r < 16; r++) acc[r] = 0.f;

    for (int k4 = 0; k4 < HDIM / 4; k4++) {
        int k = k4 * 4;
        float w0 = W[(size_t)(k + 0) * HDIM + c];
        float w1 = W[(size_t)(k + 1) * HDIM + c];
        float w2 = W[(size_t)(k + 2) * HDIM + c];
        float w3 = W[(size_t)(k + 3) * HDIM + c];
#pragma unroll
        for (int r = 0; r < 16; r++) {
            float4 xv = *(const float4*)&xsh[g * 16 + r][k];
            acc[r] = fmaf(xv.x, w0, fmaf(xv.y, w1, fmaf(xv.z, w2, fmaf(xv.w, w3, acc[r]))));
        }
    }
#pragma unroll
    for (int r = 0; r < 16; r++) {
        int gr = r0 + g * 16 + r;
        if (gr < nrows) Y[(size_t)gr * HDIM + c] = acc[r];
    }
}

// ---------- aggregation: out[i] = dinv[i]*(sum_nbr dinv[s]*h[s] + dinv[i]*h[i]) + b ----------
__global__ __launch_bounds__(128) void k_agg(const float* __restrict__ hin,
                                             float* __restrict__ hout,
                                             const int* __restrict__ ptr,
                                             const int* __restrict__ srcIdx,
                                             const float* __restrict__ dinv,
                                             const float* __restrict__ bias,
                                             int n) {
    int node = blockIdx.x;
    int f = threadIdx.x;   // 128 threads = 128 features
    __shared__ int nb[128];
    __shared__ float nd[128];
    int s = ptr[node], e = ptr[node + 1];
    float di = dinv[node];
    float acc = di * hin[(size_t)node * HDIM + f];   // self-loop (pre di-scale)
    for (int base = s; base < e; base += 128) {
        int m = min(128, e - base);
        if (f < m) {
            int sj = srcIdx[base + f];
            nb[f] = sj;
            nd[f] = dinv[sj];
        }
        __syncthreads();
        for (int j = 0; j < m; j++)
            acc = fmaf(nd[j], hin[(size_t)nb[j] * HDIM + f], acc);
        __syncthreads();
    }
    hout[(size_t)node * HDIM + f] = fmaf(di, acc, bias[f]);
}

// ---------- final FC: out[n,8] = H[n,128] @ Wfc[128,8] + bfc, fp32 output ----------
__global__ __launch_bounds__(256) void k_fc(const float* __restrict__ Hm,
                                            const float* __restrict__ Wfc,
                                            const float* __restrict__ bfc,
                                            float* __restrict__ out, int nrows) {
    __shared__ float Wsh[HDIM * CDIM];
    __shared__ float bsh[CDIM];
    int tid = threadIdx.x;
    for (int i = tid; i < HDIM * CDIM; i += 256) Wsh[i] = Wfc[i];
    if (tid < CDIM) bsh[tid] = bfc[tid];
    __syncthreads();
    int r = blockIdx.x * 32 + (tid >> 3);
    int c = tid & 7;
    if (r < nrows) {
        float acc = bsh[c];
        const float4* h4 = (const float4*)(Hm + (size_t)r * HDIM);
#pragma unroll
        for (int k4 = 0; k4 < HDIM / 4; k4++) {
            float4 v = h4[k4];
            acc = fmaf(v.x, Wsh[(4 * k4 + 0) * CDIM + c], acc);
            acc = fmaf(v.y, Wsh[(4 * k4 + 1) * CDIM + c], acc);
            acc = fmaf(v.z, Wsh[(4 * k4 + 2) * CDIM + c], acc);
            acc = fmaf(v.w, Wsh[(4 * k4 + 3) * CDIM + c], acc);
        }
        out[(size_t)r * CDIM + c] = acc;
    }
}

extern "C" void kernel_launch(void* const* d_in, const int* in_sizes, int n_in,
                              void* d_out, int out_size, void* d_ws, size_t ws_size,
                              hipStream_t stream) {
    const float* x   = (const float*)d_in[0];
    const int*   ei  = (const int*)d_in[1];
    const float* W1  = (const float*)d_in[2];
    const float* b1  = (const float*)d_in[3];
    const float* W2  = (const float*)d_in[4];
    const float* b2  = (const float*)d_in[5];
    const float* Wfc = (const float*)d_in[6];
    const float* bfc = (const float*)d_in[7];
    float* out = (float*)d_out;

    const int N = in_sizes[0] / HDIM;   // 50000
    const int E = in_sizes[1] / 2;      // 800000

    // workspace layout (~55 MB)
    float* bufA   = (float*)d_ws;                 // N*128
    float* bufB   = bufA + (size_t)N * HDIM;      // N*128
    float* dinv   = bufB + (size_t)N * HDIM;      // N
    int*   cnt    = (int*)(dinv + N);             // N
    int*   ptr    = cnt + N;                      // N+1
    int*   cursor = ptr + (N + 1);                // N
    int*   srcIdx = cursor + N;                   // E

    k_zero_int<<<(N + 255) / 256, 256, 0, stream>>>(cnt, N);
    k_hist<<<(E + 255) / 256, 256, 0, stream>>>(ei + E, cnt, E);
    k_scan<<<1, 1024, 0, stream>>>(cnt, ptr, cursor, dinv, N);
    k_scatter<<<(E + 255) / 256, 256, 0, stream>>>(ei, cursor, srcIdx, E);

    // layer 1: bufA = x@W1 ; bufB = agg(bufA) + b1
    k_gemm<<<(N + 31) / 32, 256, 0, stream>>>(x, W1, bufA, N);
    k_agg<<<N, 128, 0, stream>>>(bufA, bufB, ptr, srcIdx, dinv, b1, N);
    // layer 2: bufA = bufB@W2 ; bufB = agg(bufA) + b2
    k_gemm<<<(N + 31) / 32, 256, 0, stream>>>(bufB, W2, bufA, N);
    k_agg<<<N, 128, 0, stream>>>(bufA, bufB, ptr, srcIdx, dinv, b2, N);
    // classifier
    k_fc<<<(N + 31) / 32, 256, 0, stream>>>(bufB, Wfc, bfc, out, N);
}

// Round 5
// 390.655 us; speedup vs baseline: 1.2009x; 1.2009x over previous
//
#include <hip/hip_runtime.h>
#include <hip/hip_bf16.h>

#define HDIM 128
#define CDIM 8
#define SCAN_CHUNK 4096   // 256 threads x 16 elements

// Harness contract (pinned empirically, rounds 1-3):
//   float32 tensors  -> const float*
//   int64 edge_index -> const int*
//   output (float32) -> float*

// ---------- CSR build ----------
__global__ void k_zero_int(int* __restrict__ p, int n) {
    int i = blockIdx.x * blockDim.x + threadIdx.x;
    if (i < n) p[i] = 0;
}

__global__ void k_hist(const int* __restrict__ col, int* __restrict__ cnt, int E) {
    int e = blockIdx.x * blockDim.x + threadIdx.x;
    if (e < E) atomicAdd(&cnt[col[e]], 1);
}

// ---------- hierarchical scan (replaces 96us single-block k_scan) ----------
__global__ __launch_bounds__(256) void k_scan_partial(const int* __restrict__ cnt,
                                                      int* __restrict__ blockSums, int n) {
    int b = blockIdx.x, tid = threadIdx.x;
    int base = b * SCAN_CHUNK + tid * 16;
    int s = 0;
#pragma unroll
    for (int j = 0; j < 16; j++) {
        int i = base + j;
        if (i < n) s += cnt[i];
    }
    for (int off = 32; off; off >>= 1) s += __shfl_down(s, off, 64);
    __shared__ int wsum[4];
    int lane = tid & 63, wid = tid >> 6;
    if (lane == 0) wsum[wid] = s;
    __syncthreads();
    if (tid == 0) blockSums[b] = wsum[0] + wsum[1] + wsum[2] + wsum[3];
}

__global__ void k_scan_mid(const int* __restrict__ blockSums, int* __restrict__ blockOffs,
                           int* __restrict__ ptr_n, int B) {
    // single wave; B <= 64
    int lane = threadIdx.x;
    int v = (lane < B) ? blockSums[lane] : 0;
    int x = v;
    for (int off = 1; off < 64; off <<= 1) {
        int y = __shfl_up(x, off, 64);
        if (lane >= off) x += y;
    }
    if (lane < B) blockOffs[lane] = x - v;
    if (lane == 63) *ptr_n = x;   // grand total (= E)
}

__global__ __launch_bounds__(256) void k_scan_final(const int* __restrict__ cnt,
                                                    const int* __restrict__ blockOffs,
                                                    int* __restrict__ ptr,
                                                    int* __restrict__ cursor,
                                                    float* __restrict__ dinv, int n) {
    int b = blockIdx.x, tid = threadIdx.x;
    int base = b * SCAN_CHUNK + tid * 16;
    int v[16];
    int s = 0;
#pragma unroll
    for (int j = 0; j < 16; j++) {
        int i = base + j;
        v[j] = (i < n) ? cnt[i] : 0;
        s += v[j];
    }
    int lane = tid & 63, wid = tid >> 6;
    int x = s;
    for (int off = 1; off < 64; off <<= 1) {
        int y = __shfl_up(x, off, 64);
        if (lane >= off) x += y;
    }
    __shared__ int wtot[4];
    if (lane == 63) wtot[wid] = x;
    __syncthreads();
    int woff = 0;
    for (int w = 0; w < wid; w++) woff += wtot[w];
    int excl = blockOffs[b] + woff + (x - s);   // exclusive prefix for this thread's first elem
#pragma unroll
    for (int j = 0; j < 16; j++) {
        int i = base + j;
        if (i < n) {
            ptr[i] = excl;
            cursor[i] = excl;
            dinv[i] = rsqrtf((float)v[j] + 1.0f);   // +1 self-loop
        }
        excl += v[j];
    }
}

__global__ void k_scatter(const int* __restrict__ ei, int* __restrict__ cursor,
                          int* __restrict__ srcIdx, int E) {
    int e = blockIdx.x * blockDim.x + threadIdx.x;
    if (e < E) {
        int c = ei[(size_t)E + e];   // target (col)
        int r = ei[e];               // source (row)
        int pos = atomicAdd(&cursor[c], 1);
        srcIdx[pos] = r;
    }
}

// ---------- dense GEMM: Y[n,128] = X[n,128] @ W[128,128], fp32 ----------
__global__ __launch_bounds__(256) void k_gemm(const float* __restrict__ X,
                                              const float* __restrict__ W,
                                              float* __restrict__ Y, int nrows) {
    __shared__ float xsh[32][HDIM];
    int tid = threadIdx.x;
    int c = tid & 127;         // output column
    int g = tid >> 7;          // row-group: 0 or 1
    int r0 = blockIdx.x * 32;

    for (int idx = tid; idx < 32 * HDIM / 4; idx += 256) {
        int row = idx >> 5;
        int kk = (idx & 31) * 4;
        int gr = r0 + row;
        float4 v = make_float4(0.f, 0.f, 0.f, 0.f);
        if (gr < nrows) v = *(const float4*)(X + (size_t)gr * HDIM + kk);
        *(float4*)&xsh[row][kk] = v;
    }
    __syncthreads();

    float acc[16];
#pragma unroll
    for (int r = 0; r < 16; r++) acc[r] = 0.f;

    for (int k4 = 0; k4 < HDIM / 4; k4++) {
        int k = k4 * 4;
        float w0 = W[(size_t)(k + 0) * HDIM + c];
        float w1 = W[(size_t)(k + 1) * HDIM + c];
        float w2 = W[(size_t)(k + 2) * HDIM + c];
        float w3 = W[(size_t)(k + 3) * HDIM + c];
#pragma unroll
        for (int r = 0; r < 16; r++) {
            float4 xv = *(const float4*)&xsh[g * 16 + r][k];
            acc[r] = fmaf(xv.x, w0, fmaf(xv.y, w1, fmaf(xv.z, w2, fmaf(xv.w, w3, acc[r]))));
        }
    }
#pragma unroll
    for (int r = 0; r < 16; r++) {
        int gr = r0 + g * 16 + r;
        if (gr < nrows) Y[(size_t)gr * HDIM + c] = acc[r];
    }
}

// ---------- aggregation ----------
__global__ __launch_bounds__(128) void k_agg(const float* __restrict__ hin,
                                             float* __restrict__ hout,
                                             const int* __restrict__ ptr,
                                             const int* __restrict__ srcIdx,
                                             const float* __restrict__ dinv,
                                             const float* __restrict__ bias,
                                             int n) {
    int node = blockIdx.x;
    int f = threadIdx.x;
    __shared__ int nb[128];
    __shared__ float nd[128];
    int s = ptr[node], e = ptr[node + 1];
    float di = dinv[node];
    float acc = di * hin[(size_t)node * HDIM + f];
    for (int base = s; base < e; base += 128) {
        int m = min(128, e - base);
        if (f < m) {
            int sj = srcIdx[base + f];
            nb[f] = sj;
            nd[f] = dinv[sj];
        }
        __syncthreads();
        for (int j = 0; j < m; j++)
            acc = fmaf(nd[j], hin[(size_t)nb[j] * HDIM + f], acc);
        __syncthreads();
    }
    hout[(size_t)node * HDIM + f] = fmaf(di, acc, bias[f]);
}

// ---------- final FC ----------
__global__ __launch_bounds__(256) void k_fc(const float* __restrict__ Hm,
                                            const float* __restrict__ Wfc,
                                            const float* __restrict__ bfc,
                                            float* __restrict__ out, int nrows) {
    __shared__ float Wsh[HDIM * CDIM];
    __shared__ float bsh[CDIM];
    int tid = threadIdx.x;
    for (int i = tid; i < HDIM * CDIM; i += 256) Wsh[i] = Wfc[i];
    if (tid < CDIM) bsh[tid] = bfc[tid];
    __syncthreads();
    int r = blockIdx.x * 32 + (tid >> 3);
    int c = tid & 7;
    if (r < nrows) {
        float acc = bsh[c];
        const float4* h4 = (const float4*)(Hm + (size_t)r * HDIM);
#pragma unroll
        for (int k4 = 0; k4 < HDIM / 4; k4++) {
            float4 v = h4[k4];
            acc = fmaf(v.x, Wsh[(4 * k4 + 0) * CDIM + c], acc);
            acc = fmaf(v.y, Wsh[(4 * k4 + 1) * CDIM + c], acc);
            acc = fmaf(v.z, Wsh[(4 * k4 + 2) * CDIM + c], acc);
            acc = fmaf(v.w, Wsh[(4 * k4 + 3) * CDIM + c], acc);
        }
        out[(size_t)r * CDIM + c] = acc;
    }
}

extern "C" void kernel_launch(void* const* d_in, const int* in_sizes, int n_in,
                              void* d_out, int out_size, void* d_ws, size_t ws_size,
                              hipStream_t stream) {
    const float* x   = (const float*)d_in[0];
    const int*   ei  = (const int*)d_in[1];
    const float* W1  = (const float*)d_in[2];
    const float* b1  = (const float*)d_in[3];
    const float* W2  = (const float*)d_in[4];
    const float* b2  = (const float*)d_in[5];
    const float* Wfc = (const float*)d_in[6];
    const float* bfc = (const float*)d_in[7];
    float* out = (float*)d_out;

    const int N = in_sizes[0] / HDIM;   // 50000
    const int E = in_sizes[1] / 2;      // 800000
    const int B = (N + SCAN_CHUNK - 1) / SCAN_CHUNK;   // 13

    // workspace layout (~55 MB)
    float* bufA     = (float*)d_ws;                 // N*128
    float* bufB     = bufA + (size_t)N * HDIM;      // N*128
    float* dinv     = bufB + (size_t)N * HDIM;      // N
    int*   cnt      = (int*)(dinv + N);             // N
    int*   ptr      = cnt + N;                      // N+1
    int*   cursor   = ptr + (N + 1);                // N
    int*   srcIdx   = cursor + N;                   // E
    int*   blockSum = srcIdx + E;                   // 64
    int*   blockOff = blockSum + 64;                // 64

    k_zero_int<<<(N + 255) / 256, 256, 0, stream>>>(cnt, N);
    k_hist<<<(E + 255) / 256, 256, 0, stream>>>(ei + E, cnt, E);
    k_scan_partial<<<B, 256, 0, stream>>>(cnt, blockSum, N);
    k_scan_mid<<<1, 64, 0, stream>>>(blockSum, blockOff, ptr + N, B);
    k_scan_final<<<B, 256, 0, stream>>>(cnt, blockOff, ptr, cursor, dinv, N);
    k_scatter<<<(E + 255) / 256, 256, 0, stream>>>(ei, cursor, srcIdx, E);

    // layer 1: bufA = x@W1 ; bufB = agg(bufA) + b1
    k_gemm<<<(N + 31) / 32, 256, 0, stream>>>(x, W1, bufA, N);
    k_agg<<<N, 128, 0, stream>>>(bufA, bufB, ptr, srcIdx, dinv, b1, N);
    // layer 2: bufA = bufB@W2 ; bufB = agg(bufA) + b2
    k_gemm<<<(N + 31) / 32, 256, 0, stream>>>(bufB, W2, bufA, N);
    k_agg<<<N, 128, 0, stream>>>(bufA, bufB, ptr, srcIdx, dinv, b2, N);
    // classifier
    k_fc<<<(N + 31) / 32, 256, 0, stream>>>(bufB, Wfc, bfc, out, N);
}

// Round 6
// 365.327 us; speedup vs baseline: 1.2841x; 1.0693x over previous
//
#include <hip/hip_runtime.h>
#include <hip/hip_bf16.h>

#define HDIM 128
#define CDIM 8
#define SCAN_CHUNK 4096   // 256 threads x 16 elements

// Harness contract (pinned empirically, rounds 1-3):
//   float32 tensors  -> const float*
//   int64 edge_index -> const int*
//   output (float32) -> float*
//
// R5 profile: k_agg memory-bound (3.6 TB/s, VALUBusy 25%). This round: gathered
// intermediates (GEMM outputs) stored bf16 -> halves gather bytes. fp32 accum.

// ---------- CSR build ----------
__global__ void k_hist(const int* __restrict__ col, int* __restrict__ cnt, int E) {
    int e = blockIdx.x * blockDim.x + threadIdx.x;
    if (e < E) atomicAdd(&cnt[col[e]], 1);
}

// ---------- hierarchical scan ----------
__global__ __launch_bounds__(256) void k_scan_partial(const int* __restrict__ cnt,
                                                      int* __restrict__ blockSums, int n) {
    int b = blockIdx.x, tid = threadIdx.x;
    int base = b * SCAN_CHUNK + tid * 16;
    int s = 0;
#pragma unroll
    for (int j = 0; j < 16; j++) {
        int i = base + j;
        if (i < n) s += cnt[i];
    }
    for (int off = 32; off; off >>= 1) s += __shfl_down(s, off, 64);
    __shared__ int wsum[4];
    int lane = tid & 63, wid = tid >> 6;
    if (lane == 0) wsum[wid] = s;
    __syncthreads();
    if (tid == 0) blockSums[b] = wsum[0] + wsum[1] + wsum[2] + wsum[3];
}

__global__ void k_scan_mid(const int* __restrict__ blockSums, int* __restrict__ blockOffs,
                           int* __restrict__ ptr_n, int B) {
    int lane = threadIdx.x;
    int v = (lane < B) ? blockSums[lane] : 0;
    int x = v;
    for (int off = 1; off < 64; off <<= 1) {
        int y = __shfl_up(x, off, 64);
        if (lane >= off) x += y;
    }
    if (lane < B) blockOffs[lane] = x - v;
    if (lane == 63) *ptr_n = x;   // grand total (= E)
}

__global__ __launch_bounds__(256) void k_scan_final(const int* __restrict__ cnt,
                                                    const int* __restrict__ blockOffs,
                                                    int* __restrict__ ptr,
                                                    int* __restrict__ cursor,
                                                    float* __restrict__ dinv, int n) {
    int b = blockIdx.x, tid = threadIdx.x;
    int base = b * SCAN_CHUNK + tid * 16;
    int v[16];
    int s = 0;
#pragma unroll
    for (int j = 0; j < 16; j++) {
        int i = base + j;
        v[j] = (i < n) ? cnt[i] : 0;
        s += v[j];
    }
    int lane = tid & 63, wid = tid >> 6;
    int x = s;
    for (int off = 1; off < 64; off <<= 1) {
        int y = __shfl_up(x, off, 64);
        if (lane >= off) x += y;
    }
    __shared__ int wtot[4];
    if (lane == 63) wtot[wid] = x;
    __syncthreads();
    int woff = 0;
    for (int w = 0; w < wid; w++) woff += wtot[w];
    int excl = blockOffs[b] + woff + (x - s);
#pragma unroll
    for (int j = 0; j < 16; j++) {
        int i = base + j;
        if (i < n) {
            ptr[i] = excl;
            cursor[i] = excl;
            dinv[i] = rsqrtf((float)v[j] + 1.0f);   // +1 self-loop
        }
        excl += v[j];
    }
}

__global__ void k_scatter(const int* __restrict__ ei, int* __restrict__ cursor,
                          int* __restrict__ srcIdx, int E) {
    int e = blockIdx.x * blockDim.x + threadIdx.x;
    if (e < E) {
        int c = ei[(size_t)E + e];   // target (col)
        int r = ei[e];               // source (row)
        int pos = atomicAdd(&cursor[c], 1);
        srcIdx[pos] = r;
    }
}

// ---------- dense GEMM: Y[n,128] = X[n,128] @ W[128,128], fp32 accum, bf16 out ----------
__global__ __launch_bounds__(256) void k_gemm(const float* __restrict__ X,
                                              const float* __restrict__ W,
                                              __hip_bfloat16* __restrict__ Y, int nrows) {
    __shared__ float xsh[32][HDIM];
    int tid = threadIdx.x;
    int c = tid & 127;         // output column
    int g = tid >> 7;          // row-group: 0 or 1
    int r0 = blockIdx.x * 32;

    for (int idx = tid; idx < 32 * HDIM / 4; idx += 256) {
        int row = idx >> 5;
        int kk = (idx & 31) * 4;
        int gr = r0 + row;
        float4 v = make_float4(0.f, 0.f, 0.f, 0.f);
        if (gr < nrows) v = *(const float4*)(X + (size_t)gr * HDIM + kk);
        *(float4*)&xsh[row][kk] = v;
    }
    __syncthreads();

    float acc[16];
#pragma unroll
    for (int r = 0; r < 16; r++) acc[r] = 0.f;

    for (int k4 = 0; k4 < HDIM / 4; k4++) {
        int k = k4 * 4;
        float w0 = W[(size_t)(k + 0) * HDIM + c];
        float w1 = W[(size_t)(k + 1) * HDIM + c];
        float w2 = W[(size_t)(k + 2) * HDIM + c];
        float w3 = W[(size_t)(k + 3) * HDIM + c];
#pragma unroll
        for (int r = 0; r < 16; r++) {
            float4 xv = *(const float4*)&xsh[g * 16 + r][k];
            acc[r] = fmaf(xv.x, w0, fmaf(xv.y, w1, fmaf(xv.z, w2, fmaf(xv.w, w3, acc[r]))));
        }
    }
#pragma unroll
    for (int r = 0; r < 16; r++) {
        int gr = r0 + g * 16 + r;
        if (gr < nrows) Y[(size_t)gr * HDIM + c] = __float2bfloat16(acc[r]);
    }
}

// ---------- aggregation: gathers bf16 rows, fp32 accumulate ----------
__global__ __launch_bounds__(128) void k_agg(const __hip_bfloat16* __restrict__ hin,
                                             float* __restrict__ hout,
                                             const int* __restrict__ ptr,
                                             const int* __restrict__ srcIdx,
                                             const float* __restrict__ dinv,
                                             const float* __restrict__ bias,
                                             int n) {
    int node = blockIdx.x;
    int f = threadIdx.x;
    __shared__ int nb[128];
    __shared__ float nd[128];
    int s = ptr[node], e = ptr[node + 1];
    float di = dinv[node];
    float acc = di * __bfloat162float(hin[(size_t)node * HDIM + f]);   // self-loop
    for (int base = s; base < e; base += 128) {
        int m = min(128, e - base);
        if (f < m) {
            int sj = srcIdx[base + f];
            nb[f] = sj;
            nd[f] = dinv[sj];
        }
        __syncthreads();
        for (int j = 0; j < m; j++)
            acc = fmaf(nd[j], __bfloat162float(hin[(size_t)nb[j] * HDIM + f]), acc);
        __syncthreads();
    }
    hout[(size_t)node * HDIM + f] = fmaf(di, acc, bias[f]);
}

// ---------- final FC ----------
__global__ __launch_bounds__(256) void k_fc(const float* __restrict__ Hm,
                                            const float* __restrict__ Wfc,
                                            const float* __restrict__ bfc,
                                            float* __restrict__ out, int nrows) {
    __shared__ float Wsh[HDIM * CDIM];
    __shared__ float bsh[CDIM];
    int tid = threadIdx.x;
    for (int i = tid; i < HDIM * CDIM; i += 256) Wsh[i] = Wfc[i];
    if (tid < CDIM) bsh[tid] = bfc[tid];
    __syncthreads();
    int r = blockIdx.x * 32 + (tid >> 3);
    int c = tid & 7;
    if (r < nrows) {
        float acc = bsh[c];
        const float4* h4 = (const float4*)(Hm + (size_t)r * HDIM);
#pragma unroll
        for (int k4 = 0; k4 < HDIM / 4; k4++) {
            float4 v = h4[k4];
            acc = fmaf(v.x, Wsh[(4 * k4 + 0) * CDIM + c], acc);
            acc = fmaf(v.y, Wsh[(4 * k4 + 1) * CDIM + c], acc);
            acc = fmaf(v.z, Wsh[(4 * k4 + 2) * CDIM + c], acc);
            acc = fmaf(v.w, Wsh[(4 * k4 + 3) * CDIM + c], acc);
        }
        out[(size_t)r * CDIM + c] = acc;
    }
}

extern "C" void kernel_launch(void* const* d_in, const int* in_sizes, int n_in,
                              void* d_out, int out_size, void* d_ws, size_t ws_size,
                              hipStream_t stream) {
    const float* x   = (const float*)d_in[0];
    const int*   ei  = (const int*)d_in[1];
    const float* W1  = (const float*)d_in[2];
    const float* b1  = (const float*)d_in[3];
    const float* W2  = (const float*)d_in[4];
    const float* b2  = (const float*)d_in[5];
    const float* Wfc = (const float*)d_in[6];
    const float* bfc = (const float*)d_in[7];
    float* out = (float*)d_out;

    const int N = in_sizes[0] / HDIM;   // 50000
    const int E = in_sizes[1] / 2;      // 800000
    const int B = (N + SCAN_CHUNK - 1) / SCAN_CHUNK;   // 13

    // workspace layout
    float*          bufF  = (float*)d_ws;                      // N*128 fp32 (agg out)
    __hip_bfloat16* bufH  = (__hip_bfloat16*)(bufF + (size_t)N * HDIM);  // N*128 bf16 (gemm out)
    float* dinv     = (float*)(bufH + (size_t)N * HDIM);       // N
    int*   cnt      = (int*)(dinv + N);                        // N
    int*   ptr      = cnt + N;                                 // N+1
    int*   cursor   = ptr + (N + 1);                           // N
    int*   srcIdx   = cursor + N;                              // E
    int*   blockSum = srcIdx + E;                              // 64
    int*   blockOff = blockSum + 64;                           // 64

    hipMemsetAsync(cnt, 0, (size_t)N * sizeof(int), stream);
    k_hist<<<(E + 255) / 256, 256, 0, stream>>>(ei + E, cnt, E);
    k_scan_partial<<<B, 256, 0, stream>>>(cnt, blockSum, N);
    k_scan_mid<<<1, 64, 0, stream>>>(blockSum, blockOff, ptr + N, B);
    k_scan_final<<<B, 256, 0, stream>>>(cnt, blockOff, ptr, cursor, dinv, N);
    k_scatter<<<(E + 255) / 256, 256, 0, stream>>>(ei, cursor, srcIdx, E);

    // layer 1: bufH = bf16(x@W1) ; bufF = agg(bufH) + b1
    k_gemm<<<(N + 31) / 32, 256, 0, stream>>>(x, W1, bufH, N);
    k_agg<<<N, 128, 0, stream>>>(bufH, bufF, ptr, srcIdx, dinv, b1, N);
    // layer 2: bufH = bf16(bufF@W2) ; bufF = agg(bufH) + b2
    k_gemm<<<(N + 31) / 32, 256, 0, stream>>>(bufF, W2, bufH, N);
    k_agg<<<N, 128, 0, stream>>>(bufH, bufF, ptr, srcIdx, dinv, b2, N);
    // classifier
    k_fc<<<(N + 31) / 32, 256, 0, stream>>>(bufF, Wfc, bfc, out, N);
}

// Round 7
// 349.255 us; speedup vs baseline: 1.3432x; 1.0460x over previous
//
#include <hip/hip_runtime.h>
#include <hip/hip_bf16.h>

#define HDIM 128
#define CDIM 8
#define SCAN_CHUNK 4096   // 256 threads x 16 elements

// Harness contract (pinned empirically, rounds 1-3):
//   float32 tensors -> const float* ; int64 edge_index -> const int* ; output -> float*
//
// R6 profile: k_scatter 56us top (random 4B writes cost 64B lines: WRITE 52.6MB
// for 3.2MB payload, 1TB/s, VALU idle). ~7us/launch overhead measured across
// rounds. k_agg partially issue-bound (2B/lane gathers).
// R7: fuse scatter|gemm1 (complementary pipes), 1-launch lookback scan,
// vectorized 16B/lane agg gather. 12 -> 8 dispatches.

// ---------- histogram ----------
__global__ void k_hist(const int* __restrict__ col, int* __restrict__ cnt, int E) {
    int e = blockIdx.x * blockDim.x + threadIdx.x;
    if (e < E) atomicAdd(&cnt[col[e]], 1);
}

// ---------- single-launch decoupled-lookback scan ----------
// 13 blocks (co-resident). status[] zeroed by the same memset as cnt.
// Communication is purely through device-scope atomic values (no fence needed:
// the value itself is the message). Publishes total+1 so 0 == not-ready.
__global__ __launch_bounds__(256) void k_scan(const int* __restrict__ cnt,
                                              int* __restrict__ status,
                                              int* __restrict__ ptr,
                                              int* __restrict__ cursor,
                                              float* __restrict__ dinv,
                                              int n, int Etot) {
    int b = blockIdx.x, tid = threadIdx.x;
    int base = b * SCAN_CHUNK + tid * 16;
    int v[16];
    int s = 0;
#pragma unroll
    for (int j = 0; j < 16; j++) {
        int i = base + j;
        v[j] = (i < n) ? cnt[i] : 0;
        s += v[j];
    }
    int lane = tid & 63, wid = tid >> 6;
    int x = s;
    for (int off = 1; off < 64; off <<= 1) {
        int y = __shfl_up(x, off, 64);
        if (lane >= off) x += y;
    }
    __shared__ int wtot[4];
    __shared__ int sprefix;
    if (lane == 63) wtot[wid] = x;
    __syncthreads();
    if (tid == 0) {
        int tot = wtot[0] + wtot[1] + wtot[2] + wtot[3];
        atomicExch(&status[b], tot + 1);            // publish first (no peer deadlock)
        int pre = 0;
        for (int p = 0; p < b; p++) {
            int vv;
            do { vv = atomicAdd(&status[p], 0); } while (vv == 0);
            pre += vv - 1;
        }
        sprefix = pre;
        if (b == 0) ptr[n] = Etot;
    }
    __syncthreads();
    int woff = 0;
    for (int w = 0; w < wid; w++) woff += wtot[w];
    int excl = sprefix + woff + (x - s);
#pragma unroll
    for (int j = 0; j < 16; j++) {
        int i = base + j;
        if (i < n) {
            ptr[i] = excl;
            cursor[i] = excl;
            dinv[i] = rsqrtf((float)v[j] + 1.0f);   // +1 self-loop
        }
        excl += v[j];
    }
}

// ---------- fused: CSR scatter | dense GEMM layer-1 (independent work) ----------
// blocks [0,Gs): scatter (transaction-bound, VALU idle)
// blocks [Gs,..): Y[n,128] = bf16(X[n,128] @ W[128,128]) (VALU-bound)
__global__ __launch_bounds__(256) void k_scatter_gemm(const int* __restrict__ ei,
                                                      int* __restrict__ cursor,
                                                      int* __restrict__ srcIdx, int E,
                                                      const float* __restrict__ X,
                                                      const float* __restrict__ W,
                                                      __hip_bfloat16* __restrict__ Y,
                                                      int nrows, int Gs) {
    int tid = threadIdx.x;
    if ((int)blockIdx.x < Gs) {
        int e = blockIdx.x * 256 + tid;
        if (e < E) {
            int c = ei[(size_t)E + e];   // target
            int r = ei[e];               // source
            srcIdx[atomicAdd(&cursor[c], 1)] = r;
        }
    } else {
        __shared__ float xsh[32][HDIM];
        int bid = blockIdx.x - Gs;
        int c = tid & 127;
        int g = tid >> 7;
        int r0 = bid * 32;
        for (int idx = tid; idx < 32 * HDIM / 4; idx += 256) {
            int row = idx >> 5;
            int kk = (idx & 31) * 4;
            int gr = r0 + row;
            float4 v = make_float4(0.f, 0.f, 0.f, 0.f);
            if (gr < nrows) v = *(const float4*)(X + (size_t)gr * HDIM + kk);
            *(float4*)&xsh[row][kk] = v;
        }
        __syncthreads();
        float acc[16];
#pragma unroll
        for (int r = 0; r < 16; r++) acc[r] = 0.f;
        for (int k4 = 0; k4 < HDIM / 4; k4++) {
            int k = k4 * 4;
            float w0 = W[(size_t)(k + 0) * HDIM + c];
            float w1 = W[(size_t)(k + 1) * HDIM + c];
            float w2 = W[(size_t)(k + 2) * HDIM + c];
            float w3 = W[(size_t)(k + 3) * HDIM + c];
#pragma unroll
            for (int r = 0; r < 16; r++) {
                float4 xv = *(const float4*)&xsh[g * 16 + r][k];
                acc[r] = fmaf(xv.x, w0, fmaf(xv.y, w1, fmaf(xv.z, w2, fmaf(xv.w, w3, acc[r]))));
            }
        }
#pragma unroll
        for (int r = 0; r < 16; r++) {
            int gr = r0 + g * 16 + r;
            if (gr < nrows) Y[(size_t)gr * HDIM + c] = __float2bfloat16(acc[r]);
        }
    }
}

// ---------- standalone GEMM (layer 2) ----------
__global__ __launch_bounds__(256) void k_gemm(const float* __restrict__ X,
                                              const float* __restrict__ W,
                                              __hip_bfloat16* __restrict__ Y, int nrows) {
    __shared__ float xsh[32][HDIM];
    int tid = threadIdx.x;
    int c = tid & 127;
    int g = tid >> 7;
    int r0 = blockIdx.x * 32;
    for (int idx = tid; idx < 32 * HDIM / 4; idx += 256) {
        int row = idx >> 5;
        int kk = (idx & 31) * 4;
        int gr = r0 + row;
        float4 v = make_float4(0.f, 0.f, 0.f, 0.f);
        if (gr < nrows) v = *(const float4*)(X + (size_t)gr * HDIM + kk);
        *(float4*)&xsh[row][kk] = v;
    }
    __syncthreads();
    float acc[16];
#pragma unroll
    for (int r = 0; r < 16; r++) acc[r] = 0.f;
    for (int k4 = 0; k4 < HDIM / 4; k4++) {
        int k = k4 * 4;
        float w0 = W[(size_t)(k + 0) * HDIM + c];
        float w1 = W[(size_t)(k + 1) * HDIM + c];
        float w2 = W[(size_t)(k + 2) * HDIM + c];
        float w3 = W[(size_t)(k + 3) * HDIM + c];
#pragma unroll
        for (int r = 0; r < 16; r++) {
            float4 xv = *(const float4*)&xsh[g * 16 + r][k];
            acc[r] = fmaf(xv.x, w0, fmaf(xv.y, w1, fmaf(xv.z, w2, fmaf(xv.w, w3, acc[r]))));
        }
    }
#pragma unroll
    for (int r = 0; r < 16; r++) {
        int gr = r0 + g * 16 + r;
        if (gr < nrows) Y[(size_t)gr * HDIM + c] = __float2bfloat16(acc[r]);
    }
}

// ---------- aggregation, vectorized 16B/lane gathers ----------
// 128 threads/node: fs = t&15 owns features fs*8..fs*8+7, jg = t>>4 is an
// 8-way split of the edge range. Each lane loads uint4 = 8 bf16 per edge.
// 4KB LDS cross-jg reduction at the end.
__device__ __forceinline__ void bf8_fma(uint4 q, float w, float* acc) {
    unsigned u[4] = {q.x, q.y, q.z, q.w};
#pragma unroll
    for (int i = 0; i < 4; i++) {
        float lo = __uint_as_float(u[i] << 16);
        float hi = __uint_as_float(u[i] & 0xFFFF0000u);
        acc[2 * i]     = fmaf(w, lo, acc[2 * i]);
        acc[2 * i + 1] = fmaf(w, hi, acc[2 * i + 1]);
    }
}

__global__ __launch_bounds__(128) void k_agg(const __hip_bfloat16* __restrict__ hin,
                                             float* __restrict__ hout,
                                             const int* __restrict__ ptr,
                                             const int* __restrict__ srcIdx,
                                             const float* __restrict__ dinv,
                                             const float* __restrict__ bias,
                                             int n) {
    int node = blockIdx.x;
    int t = threadIdx.x;
    int fs = t & 15, jg = t >> 4;
    int s = ptr[node], e = ptr[node + 1];
    float di = dinv[node];
    float acc[8];
#pragma unroll
    for (int k = 0; k < 8; k++) acc[k] = 0.f;

    if (jg == 0) {  // self-loop contribution (weight di, pre final di-scale)
        uint4 q = ((const uint4*)(hin + (size_t)node * HDIM))[fs];
        bf8_fma(q, di, acc);
    }
    for (int jj = s + jg; jj < e; jj += 8) {
        int sj = srcIdx[jj];
        float w = dinv[sj];
        uint4 q = ((const uint4*)(hin + (size_t)sj * HDIM))[fs];
        bf8_fma(q, w, acc);
    }

    __shared__ float red[8][HDIM];
#pragma unroll
    for (int k = 0; k < 8; k++) red[jg][fs * 8 + k] = acc[k];
    __syncthreads();
    int f = t;
    float sum = 0.f;
#pragma unroll
    for (int j = 0; j < 8; j++) sum += red[j][f];
    hout[(size_t)node * HDIM + f] = fmaf(di, sum, bias[f]);
}

// ---------- final FC ----------
__global__ __launch_bounds__(256) void k_fc(const float* __restrict__ Hm,
                                            const float* __restrict__ Wfc,
                                            const float* __restrict__ bfc,
                                            float* __restrict__ out, int nrows) {
    __shared__ float Wsh[HDIM * CDIM];
    __shared__ float bsh[CDIM];
    int tid = threadIdx.x;
    for (int i = tid; i < HDIM * CDIM; i += 256) Wsh[i] = Wfc[i];
    if (tid < CDIM) bsh[tid] = bfc[tid];
    __syncthreads();
    int r = blockIdx.x * 32 + (tid >> 3);
    int c = tid & 7;
    if (r < nrows) {
        float acc = bsh[c];
        const float4* h4 = (const float4*)(Hm + (size_t)r * HDIM);
#pragma unroll
        for (int k4 = 0; k4 < HDIM / 4; k4++) {
            float4 v = h4[k4];
            acc = fmaf(v.x, Wsh[(4 * k4 + 0) * CDIM + c], acc);
            acc = fmaf(v.y, Wsh[(4 * k4 + 1) * CDIM + c], acc);
            acc = fmaf(v.z, Wsh[(4 * k4 + 2) * CDIM + c], acc);
            acc = fmaf(v.w, Wsh[(4 * k4 + 3) * CDIM + c], acc);
        }
        out[(size_t)r * CDIM + c] = acc;
    }
}

extern "C" void kernel_launch(void* const* d_in, const int* in_sizes, int n_in,
                              void* d_out, int out_size, void* d_ws, size_t ws_size,
                              hipStream_t stream) {
    const float* x   = (const float*)d_in[0];
    const int*   ei  = (const int*)d_in[1];
    const float* W1  = (const float*)d_in[2];
    const float* b1  = (const float*)d_in[3];
    const float* W2  = (const float*)d_in[4];
    const float* b2  = (const float*)d_in[5];
    const float* Wfc = (const float*)d_in[6];
    const float* bfc = (const float*)d_in[7];
    float* out = (float*)d_out;

    const int N = in_sizes[0] / HDIM;   // 50000
    const int E = in_sizes[1] / 2;      // 800000
    const int B = (N + SCAN_CHUNK - 1) / SCAN_CHUNK;   // 13

    // workspace layout
    float*          bufF = (float*)d_ws;                                  // N*128 fp32
    __hip_bfloat16* bufH = (__hip_bfloat16*)(bufF + (size_t)N * HDIM);    // N*128 bf16
    float* dinv   = (float*)(bufH + (size_t)N * HDIM);  // N
    int*   cnt    = (int*)(dinv + N);                   // N      } zeroed together
    int*   status = cnt + N;                            // 16     }
    int*   ptr    = status + 16;                        // N+1
    int*   cursor = ptr + (N + 1);                      // N
    int*   srcIdx = cursor + N;                         // E

    hipMemsetAsync(cnt, 0, (size_t)(N + 16) * sizeof(int), stream);
    k_hist<<<(E + 255) / 256, 256, 0, stream>>>(ei + E, cnt, E);
    k_scan<<<B, 256, 0, stream>>>(cnt, status, ptr, cursor, dinv, N, E);

    const int Gs = (E + 255) / 256;        // scatter blocks (first: longer pole)
    const int Gg = (N + 31) / 32;          // gemm blocks
    k_scatter_gemm<<<Gs + Gg, 256, 0, stream>>>(ei, cursor, srcIdx, E, x, W1, bufH, N, Gs);

    k_agg<<<N, 128, 0, stream>>>(bufH, bufF, ptr, srcIdx, dinv, b1, N);
    k_gemm<<<Gg, 256, 0, stream>>>(bufF, W2, bufH, N);
    k_agg<<<N, 128, 0, stream>>>(bufH, bufF, ptr, srcIdx, dinv, b2, N);
    k_fc<<<(N + 31) / 32, 256, 0, stream>>>(bufF, Wfc, bfc, out, N);
}

// Round 8
// 337.579 us; speedup vs baseline: 1.3897x; 1.0346x over previous
//
#include <hip/hip_runtime.h>
#include <hip/hip_bf16.h>

#define HDIM 128
#define CDIM 8
#define SCAN_CHUNK 4096   // 256 threads x 16 elements

// Harness contract (pinned empirically, rounds 1-3):
//   float32 tensors -> const float* ; int64 edge_index -> const int* ; output -> float*
//
// R7 post-mortem: scatter|gemm fusion with [0,Gs)=scatter block split did NOT
// overlap (103us = 57+46 serial: blocks dispatch in index order, phases drain
// sequentially). R8: stripe-interleave roles (b%3: 2 scatter + 1 gemm) so both
// kinds are co-resident; fuse FC into agg layer-2 epilogue (saves k_fc launch
// + 51MB bufF roundtrip).

// ---------- histogram ----------
__global__ void k_hist(const int* __restrict__ col, int* __restrict__ cnt, int E) {
    int e = blockIdx.x * blockDim.x + threadIdx.x;
    if (e < E) atomicAdd(&cnt[col[e]], 1);
}

// ---------- single-launch decoupled-lookback scan (13 co-resident blocks) ----------
__global__ __launch_bounds__(256) void k_scan(const int* __restrict__ cnt,
                                              int* __restrict__ status,
                                              int* __restrict__ ptr,
                                              int* __restrict__ cursor,
                                              float* __restrict__ dinv,
                                              int n, int Etot) {
    int b = blockIdx.x, tid = threadIdx.x;
    int base = b * SCAN_CHUNK + tid * 16;
    int v[16];
    int s = 0;
#pragma unroll
    for (int j = 0; j < 16; j++) {
        int i = base + j;
        v[j] = (i < n) ? cnt[i] : 0;
        s += v[j];
    }
    int lane = tid & 63, wid = tid >> 6;
    int x = s;
    for (int off = 1; off < 64; off <<= 1) {
        int y = __shfl_up(x, off, 64);
        if (lane >= off) x += y;
    }
    __shared__ int wtot[4];
    __shared__ int sprefix;
    if (lane == 63) wtot[wid] = x;
    __syncthreads();
    if (tid == 0) {
        int tot = wtot[0] + wtot[1] + wtot[2] + wtot[3];
        atomicExch(&status[b], tot + 1);            // publish first (no peer deadlock)
        int pre = 0;
        for (int p = 0; p < b; p++) {
            int vv;
            do { vv = atomicAdd(&status[p], 0); } while (vv == 0);
            pre += vv - 1;
        }
        sprefix = pre;
        if (b == 0) ptr[n] = Etot;
    }
    __syncthreads();
    int woff = 0;
    for (int w = 0; w < wid; w++) woff += wtot[w];
    int excl = sprefix + woff + (x - s);
#pragma unroll
    for (int j = 0; j < 16; j++) {
        int i = base + j;
        if (i < n) {
            ptr[i] = excl;
            cursor[i] = excl;
            dinv[i] = rsqrtf((float)v[j] + 1.0f);   // +1 self-loop
        }
        excl += v[j];
    }
}

// ---------- fused scatter | gemm, stripe-interleaved for co-residency ----------
// Launch 3*Gg blocks. b%3 in {0,1}: scatter block (idx 2q+k, needs 2*Gg >= Gs);
// b%3 == 2: gemm block q. Both roles resident at all times -> pipe overlap.
__global__ __launch_bounds__(256) void k_scatter_gemm(const int* __restrict__ ei,
                                                      int* __restrict__ cursor,
                                                      int* __restrict__ srcIdx, int E,
                                                      const float* __restrict__ X,
                                                      const float* __restrict__ W,
                                                      __hip_bfloat16* __restrict__ Y,
                                                      int nrows) {
    int tid = threadIdx.x;
    int q = blockIdx.x / 3, k3 = blockIdx.x % 3;
    if (k3 < 2) {
        int e = (2 * q + k3) * 256 + tid;
        if (e < E) {
            int c = ei[(size_t)E + e];   // target
            int r = ei[e];               // source
            srcIdx[atomicAdd(&cursor[c], 1)] = r;
        }
    } else {
        __shared__ float xsh[32][HDIM];
        int c = tid & 127;
        int g = tid >> 7;
        int r0 = q * 32;
        for (int idx = tid; idx < 32 * HDIM / 4; idx += 256) {
            int row = idx >> 5;
            int kk = (idx & 31) * 4;
            int gr = r0 + row;
            float4 v = make_float4(0.f, 0.f, 0.f, 0.f);
            if (gr < nrows) v = *(const float4*)(X + (size_t)gr * HDIM + kk);
            *(float4*)&xsh[row][kk] = v;
        }
        __syncthreads();
        float acc[16];
#pragma unroll
        for (int r = 0; r < 16; r++) acc[r] = 0.f;
        for (int k4 = 0; k4 < HDIM / 4; k4++) {
            int k = k4 * 4;
            float w0 = W[(size_t)(k + 0) * HDIM + c];
            float w1 = W[(size_t)(k + 1) * HDIM + c];
            float w2 = W[(size_t)(k + 2) * HDIM + c];
            float w3 = W[(size_t)(k + 3) * HDIM + c];
#pragma unroll
            for (int r = 0; r < 16; r++) {
                float4 xv = *(const float4*)&xsh[g * 16 + r][k];
                acc[r] = fmaf(xv.x, w0, fmaf(xv.y, w1, fmaf(xv.z, w2, fmaf(xv.w, w3, acc[r]))));
            }
        }
#pragma unroll
        for (int r = 0; r < 16; r++) {
            int gr = r0 + g * 16 + r;
            if (gr < nrows) Y[(size_t)gr * HDIM + c] = __float2bfloat16(acc[r]);
        }
    }
}

// ---------- standalone GEMM (layer 2) ----------
__global__ __launch_bounds__(256) void k_gemm(const float* __restrict__ X,
                                              const float* __restrict__ W,
                                              __hip_bfloat16* __restrict__ Y, int nrows) {
    __shared__ float xsh[32][HDIM];
    int tid = threadIdx.x;
    int c = tid & 127;
    int g = tid >> 7;
    int r0 = blockIdx.x * 32;
    for (int idx = tid; idx < 32 * HDIM / 4; idx += 256) {
        int row = idx >> 5;
        int kk = (idx & 31) * 4;
        int gr = r0 + row;
        float4 v = make_float4(0.f, 0.f, 0.f, 0.f);
        if (gr < nrows) v = *(const float4*)(X + (size_t)gr * HDIM + kk);
        *(float4*)&xsh[row][kk] = v;
    }
    __syncthreads();
    float acc[16];
#pragma unroll
    for (int r = 0; r < 16; r++) acc[r] = 0.f;
    for (int k4 = 0; k4 < HDIM / 4; k4++) {
        int k = k4 * 4;
        float w0 = W[(size_t)(k + 0) * HDIM + c];
        float w1 = W[(size_t)(k + 1) * HDIM + c];
        float w2 = W[(size_t)(k + 2) * HDIM + c];
        float w3 = W[(size_t)(k + 3) * HDIM + c];
#pragma unroll
        for (int r = 0; r < 16; r++) {
            float4 xv = *(const float4*)&xsh[g * 16 + r][k];
            acc[r] = fmaf(xv.x, w0, fmaf(xv.y, w1, fmaf(xv.z, w2, fmaf(xv.w, w3, acc[r]))));
        }
    }
#pragma unroll
    for (int r = 0; r < 16; r++) {
        int gr = r0 + g * 16 + r;
        if (gr < nrows) Y[(size_t)gr * HDIM + c] = __float2bfloat16(acc[r]);
    }
}

// ---------- aggregation, vectorized 16B/lane gathers ----------
__device__ __forceinline__ void bf8_fma(uint4 q, float w, float* acc) {
    unsigned u[4] = {q.x, q.y, q.z, q.w};
#pragma unroll
    for (int i = 0; i < 4; i++) {
        float lo = __uint_as_float(u[i] << 16);
        float hi = __uint_as_float(u[i] & 0xFFFF0000u);
        acc[2 * i]     = fmaf(w, lo, acc[2 * i]);
        acc[2 * i + 1] = fmaf(w, hi, acc[2 * i + 1]);
    }
}

__global__ __launch_bounds__(128) void k_agg(const __hip_bfloat16* __restrict__ hin,
                                             float* __restrict__ hout,
                                             const int* __restrict__ ptr,
                                             const int* __restrict__ srcIdx,
                                             const float* __restrict__ dinv,
                                             const float* __restrict__ bias,
                                             int n) {
    int node = blockIdx.x;
    int t = threadIdx.x;
    int fs = t & 15, jg = t >> 4;
    int s = ptr[node], e = ptr[node + 1];
    float di = dinv[node];
    float acc[8];
#pragma unroll
    for (int k = 0; k < 8; k++) acc[k] = 0.f;

    if (jg == 0) {  // self-loop
        uint4 q = ((const uint4*)(hin + (size_t)node * HDIM))[fs];
        bf8_fma(q, di, acc);
    }
    for (int jj = s + jg; jj < e; jj += 8) {
        int sj = srcIdx[jj];
        float w = dinv[sj];
        uint4 q = ((const uint4*)(hin + (size_t)sj * HDIM))[fs];
        bf8_fma(q, w, acc);
    }

    __shared__ float red[8][HDIM];
#pragma unroll
    for (int k = 0; k < 8; k++) red[jg][fs * 8 + k] = acc[k];
    __syncthreads();
    int f = t;
    float sum = 0.f;
#pragma unroll
    for (int j = 0; j < 8; j++) sum += red[j][f];
    hout[(size_t)node * HDIM + f] = fmaf(di, sum, bias[f]);
}

// ---------- aggregation layer-2 with fused FC epilogue ----------
__global__ __launch_bounds__(128) void k_agg_fc(const __hip_bfloat16* __restrict__ hin,
                                                const int* __restrict__ ptr,
                                                const int* __restrict__ srcIdx,
                                                const float* __restrict__ dinv,
                                                const float* __restrict__ bias,
                                                const float* __restrict__ Wfc,
                                                const float* __restrict__ bfc,
                                                float* __restrict__ out, int n) {
    int node = blockIdx.x;
    int t = threadIdx.x;
    int fs = t & 15, jg = t >> 4;
    int s = ptr[node], e = ptr[node + 1];
    float di = dinv[node];
    float acc[8];
#pragma unroll
    for (int k = 0; k < 8; k++) acc[k] = 0.f;

    if (jg == 0) {
        uint4 q = ((const uint4*)(hin + (size_t)node * HDIM))[fs];
        bf8_fma(q, di, acc);
    }
    for (int jj = s + jg; jj < e; jj += 8) {
        int sj = srcIdx[jj];
        float w = dinv[sj];
        uint4 q = ((const uint4*)(hin + (size_t)sj * HDIM))[fs];
        bf8_fma(q, w, acc);
    }

    __shared__ float red[8][HDIM];
#pragma unroll
    for (int k = 0; k < 8; k++) red[jg][fs * 8 + k] = acc[k];
    __syncthreads();
    int f = t;
    float sum = 0.f;
#pragma unroll
    for (int j = 0; j < 8; j++) sum += red[j][f];
    float val = fmaf(di, sum, bias[f]);   // h2[node][f]
    // each element red[0][f] is written only by thread t==f (its sole reader above)
    red[0][f] = val;
    __syncthreads();
    if (t < CDIM) {
        float a = bfc[t];
        for (int f2 = 0; f2 < HDIM; f2++)
            a = fmaf(red[0][f2], Wfc[(size_t)f2 * CDIM + t], a);   // Wfc L1-hot
        out[(size_t)node * CDIM + t] = a;
    }
}

extern "C" void kernel_launch(void* const* d_in, const int* in_sizes, int n_in,
                              void* d_out, int out_size, void* d_ws, size_t ws_size,
                              hipStream_t stream) {
    const float* x   = (const float*)d_in[0];
    const int*   ei  = (const int*)d_in[1];
    const float* W1  = (const float*)d_in[2];
    const float* b1  = (const float*)d_in[3];
    const float* W2  = (const float*)d_in[4];
    const float* b2  = (const float*)d_in[5];
    const float* Wfc = (const float*)d_in[6];
    const float* bfc = (const float*)d_in[7];
    float* out = (float*)d_out;

    const int N = in_sizes[0] / HDIM;   // 50000
    const int E = in_sizes[1] / 2;      // 800000
    const int B = (N + SCAN_CHUNK - 1) / SCAN_CHUNK;   // 13

    // workspace layout
    float*          bufF = (float*)d_ws;                                  // N*128 fp32
    __hip_bfloat16* bufH = (__hip_bfloat16*)(bufF + (size_t)N * HDIM);    // N*128 bf16
    float* dinv   = (float*)(bufH + (size_t)N * HDIM);  // N
    int*   cnt    = (int*)(dinv + N);                   // N      } zeroed together
    int*   status = cnt + N;                            // 16     }
    int*   ptr    = status + 16;                        // N+1
    int*   cursor = ptr + (N + 1);                      // N
    int*   srcIdx = cursor + N;                         // E

    hipMemsetAsync(cnt, 0, (size_t)(N + 16) * sizeof(int), stream);
    k_hist<<<(E + 255) / 256, 256, 0, stream>>>(ei + E, cnt, E);
    k_scan<<<B, 256, 0, stream>>>(cnt, status, ptr, cursor, dinv, N, E);

    const int Gg = (N + 31) / 32;          // 1563 gemm blocks; 2*Gg=3126 >= 3125 scatter
    k_scatter_gemm<<<3 * Gg, 256, 0, stream>>>(ei, cursor, srcIdx, E, x, W1, bufH, N);

    k_agg<<<N, 128, 0, stream>>>(bufH, bufF, ptr, srcIdx, dinv, b1, N);
    k_gemm<<<Gg, 256, 0, stream>>>(bufF, W2, bufH, N);
    k_agg_fc<<<N, 128, 0, stream>>>(bufH, ptr, srcIdx, dinv, b2, Wfc, bfc, out, N);
}

// Round 9
// 329.565 us; speedup vs baseline: 1.4235x; 1.0243x over previous
//
#include <hip/hip_runtime.h>
#include <hip/hip_bf16.h>

#define HDIM 128
#define CDIM 8
#define SCAN_CHUNK 4096   // 256 threads x 16 elements

// Harness contract (pinned empirically, rounds 1-3):
//   float32 tensors -> const float* ; int64 edge_index -> const int* ; output -> float*
//
// R8 post-mortem: k_agg_fc 79us = latency-bound (hbm 14%, VALU 30%) with
// 1.6M LDS bank conflicts (red[jg][fs*8+k] hits 4 banks, 16-way) + a
// 128-iter serial FC tail on 8 lanes. R9: wave-per-node agg, shfl_xor
// reduction (no LDS), (src,dinv) packed int2 in scatter (kills one dependent
// load per edge), all-lane FC epilogue.

// ---------- histogram ----------
__global__ void k_hist(const int* __restrict__ col, int* __restrict__ cnt, int E) {
    int e = blockIdx.x * blockDim.x + threadIdx.x;
    if (e < E) atomicAdd(&cnt[col[e]], 1);
}

// ---------- single-launch decoupled-lookback scan (13 co-resident blocks) ----------
__global__ __launch_bounds__(256) void k_scan(const int* __restrict__ cnt,
                                              int* __restrict__ status,
                                              int* __restrict__ ptr,
                                              int* __restrict__ cursor,
                                              float* __restrict__ dinv,
                                              int n, int Etot) {
    int b = blockIdx.x, tid = threadIdx.x;
    int base = b * SCAN_CHUNK + tid * 16;
    int v[16];
    int s = 0;
#pragma unroll
    for (int j = 0; j < 16; j++) {
        int i = base + j;
        v[j] = (i < n) ? cnt[i] : 0;
        s += v[j];
    }
    int lane = tid & 63, wid = tid >> 6;
    int x = s;
    for (int off = 1; off < 64; off <<= 1) {
        int y = __shfl_up(x, off, 64);
        if (lane >= off) x += y;
    }
    __shared__ int wtot[4];
    __shared__ int sprefix;
    if (lane == 63) wtot[wid] = x;
    __syncthreads();
    if (tid == 0) {
        int tot = wtot[0] + wtot[1] + wtot[2] + wtot[3];
        atomicExch(&status[b], tot + 1);            // publish first (no peer deadlock)
        int pre = 0;
        for (int p = 0; p < b; p++) {
            int vv;
            do { vv = atomicAdd(&status[p], 0); } while (vv == 0);
            pre += vv - 1;
        }
        sprefix = pre;
        if (b == 0) ptr[n] = Etot;
    }
    __syncthreads();
    int woff = 0;
    for (int w = 0; w < wid; w++) woff += wtot[w];
    int excl = sprefix + woff + (x - s);
#pragma unroll
    for (int j = 0; j < 16; j++) {
        int i = base + j;
        if (i < n) {
            ptr[i] = excl;
            cursor[i] = excl;
            dinv[i] = rsqrtf((float)v[j] + 1.0f);   // +1 self-loop
        }
        excl += v[j];
    }
}

// ---------- fused scatter | gemm, stripe-interleaved for co-residency ----------
// b%3 in {0,1}: scatter block 2q+k (2*Gg >= Gs); b%3==2: gemm block q.
// Scatter packs (src, dinv[src]) as int2 so agg needs one load per edge.
__global__ __launch_bounds__(256) void k_scatter_gemm(const int* __restrict__ ei,
                                                      int* __restrict__ cursor,
                                                      int2* __restrict__ srcW, int E,
                                                      const float* __restrict__ dinv,
                                                      const float* __restrict__ X,
                                                      const float* __restrict__ W,
                                                      __hip_bfloat16* __restrict__ Y,
                                                      int nrows) {
    int tid = threadIdx.x;
    int q = blockIdx.x / 3, k3 = blockIdx.x % 3;
    if (k3 < 2) {
        int e = (2 * q + k3) * 256 + tid;
        if (e < E) {
            int c = ei[(size_t)E + e];   // target
            int r = ei[e];               // source
            int pos = atomicAdd(&cursor[c], 1);
            srcW[pos] = make_int2(r, __float_as_int(dinv[r]));
        }
    } else {
        __shared__ float xsh[32][HDIM];
        int c = tid & 127;
        int g = tid >> 7;
        int r0 = q * 32;
        for (int idx = tid; idx < 32 * HDIM / 4; idx += 256) {
            int row = idx >> 5;
            int kk = (idx & 31) * 4;
            int gr = r0 + row;
            float4 v = make_float4(0.f, 0.f, 0.f, 0.f);
            if (gr < nrows) v = *(const float4*)(X + (size_t)gr * HDIM + kk);
            *(float4*)&xsh[row][kk] = v;
        }
        __syncthreads();
        float acc[16];
#pragma unroll
        for (int r = 0; r < 16; r++) acc[r] = 0.f;
        for (int k4 = 0; k4 < HDIM / 4; k4++) {
            int k = k4 * 4;
            float w0 = W[(size_t)(k + 0) * HDIM + c];
            float w1 = W[(size_t)(k + 1) * HDIM + c];
            float w2 = W[(size_t)(k + 2) * HDIM + c];
            float w3 = W[(size_t)(k + 3) * HDIM + c];
#pragma unroll
            for (int r = 0; r < 16; r++) {
                float4 xv = *(const float4*)&xsh[g * 16 + r][k];
                acc[r] = fmaf(xv.x, w0, fmaf(xv.y, w1, fmaf(xv.z, w2, fmaf(xv.w, w3, acc[r]))));
            }
        }
#pragma unroll
        for (int r = 0; r < 16; r++) {
            int gr = r0 + g * 16 + r;
            if (gr < nrows) Y[(size_t)gr * HDIM + c] = __float2bfloat16(acc[r]);
        }
    }
}

// ---------- standalone GEMM (layer 2) ----------
__global__ __launch_bounds__(256) void k_gemm(const float* __restrict__ X,
                                              const float* __restrict__ W,
                                              __hip_bfloat16* __restrict__ Y, int nrows) {
    __shared__ float xsh[32][HDIM];
    int tid = threadIdx.x;
    int c = tid & 127;
    int g = tid >> 7;
    int r0 = blockIdx.x * 32;
    for (int idx = tid; idx < 32 * HDIM / 4; idx += 256) {
        int row = idx >> 5;
        int kk = (idx & 31) * 4;
        int gr = r0 + row;
        float4 v = make_float4(0.f, 0.f, 0.f, 0.f);
        if (gr < nrows) v = *(const float4*)(X + (size_t)gr * HDIM + kk);
        *(float4*)&xsh[row][kk] = v;
    }
    __syncthreads();
    float acc[16];
#pragma unroll
    for (int r = 0; r < 16; r++) acc[r] = 0.f;
    for (int k4 = 0; k4 < HDIM / 4; k4++) {
        int k = k4 * 4;
        float w0 = W[(size_t)(k + 0) * HDIM + c];
        float w1 = W[(size_t)(k + 1) * HDIM + c];
        float w2 = W[(size_t)(k + 2) * HDIM + c];
        float w3 = W[(size_t)(k + 3) * HDIM + c];
#pragma unroll
        for (int r = 0; r < 16; r++) {
            float4 xv = *(const float4*)&xsh[g * 16 + r][k];
            acc[r] = fmaf(xv.x, w0, fmaf(xv.y, w1, fmaf(xv.z, w2, fmaf(xv.w, w3, acc[r]))));
        }
    }
#pragma unroll
    for (int r = 0; r < 16; r++) {
        int gr = r0 + g * 16 + r;
        if (gr < nrows) Y[(size_t)gr * HDIM + c] = __float2bfloat16(acc[r]);
    }
}

// ---------- wave-per-node aggregation core ----------
// lane = t&63; fs = lane&15 owns features fs*8..fs*8+7 (16B uint4 of the row);
// jg = lane>>4 is a 4-way edge split. shfl_xor(16,32) reduces across jg ->
// ALL lanes end with the full sum for their feature slice. No LDS.
__device__ __forceinline__ void bf8_fma(uint4 qv, float w, float* acc) {
    unsigned u[4] = {qv.x, qv.y, qv.z, qv.w};
#pragma unroll
    for (int i = 0; i < 4; i++) {
        float lo = __uint_as_float(u[i] << 16);
        float hi = __uint_as_float(u[i] & 0xFFFF0000u);
        acc[2 * i]     = fmaf(w, lo, acc[2 * i]);
        acc[2 * i + 1] = fmaf(w, hi, acc[2 * i + 1]);
    }
}

__device__ __forceinline__ void agg_core(const __hip_bfloat16* __restrict__ hin,
                                         const int* __restrict__ ptr,
                                         const int2* __restrict__ srcW,
                                         int node, int fs, int jg, float di,
                                         float* acc) {
#pragma unroll
    for (int k = 0; k < 8; k++) acc[k] = 0.f;
    if (jg == 0) {   // self-loop, weight di (final di applied by caller)
        uint4 qv = ((const uint4*)(hin + (size_t)node * HDIM))[fs];
        bf8_fma(qv, di, acc);
    }
    int s = ptr[node], e = ptr[node + 1];
    int jj = s + jg;
    bool valid = jj < e;
    int2 p = valid ? srcW[jj] : make_int2(0, 0);
    while (valid) {
        int2 cur = p;
        jj += 4;
        valid = jj < e;
        if (valid) p = srcW[jj];          // prefetch next (src, w)
        uint4 qv = ((const uint4*)(hin + (size_t)cur.x * HDIM))[fs];
        bf8_fma(qv, __int_as_float(cur.y), acc);
    }
#pragma unroll
    for (int k = 0; k < 8; k++) {
        acc[k] += __shfl_xor(acc[k], 16, 64);
        acc[k] += __shfl_xor(acc[k], 32, 64);
    }
}

// ---------- agg layer 1: fp32 output rows ----------
__global__ __launch_bounds__(256) void k_agg(const __hip_bfloat16* __restrict__ hin,
                                             float* __restrict__ hout,
                                             const int* __restrict__ ptr,
                                             const int2* __restrict__ srcW,
                                             const float* __restrict__ dinv,
                                             const float* __restrict__ bias,
                                             int n) {
    int node = blockIdx.x * 4 + (threadIdx.x >> 6);
    if (node >= n) return;
    int lane = threadIdx.x & 63;
    int fs = lane & 15, jg = lane >> 4;
    float di = dinv[node];
    float acc[8];
    agg_core(hin, ptr, srcW, node, fs, jg, di, acc);
    if (jg == 0) {
        const float4* b4 = (const float4*)bias;
        float4 bb0 = b4[fs * 2], bb1 = b4[fs * 2 + 1];
        float4 v0 = make_float4(fmaf(di, acc[0], bb0.x), fmaf(di, acc[1], bb0.y),
                                fmaf(di, acc[2], bb0.z), fmaf(di, acc[3], bb0.w));
        float4 v1 = make_float4(fmaf(di, acc[4], bb1.x), fmaf(di, acc[5], bb1.y),
                                fmaf(di, acc[6], bb1.z), fmaf(di, acc[7], bb1.w));
        float4* o4 = (float4*)(hout + (size_t)node * HDIM);
        o4[fs * 2] = v0;
        o4[fs * 2 + 1] = v1;
    }
}

// ---------- agg layer 2 + fused FC: out[node][0..7] ----------
__global__ __launch_bounds__(256) void k_agg_fc(const __hip_bfloat16* __restrict__ hin,
                                                const int* __restrict__ ptr,
                                                const int2* __restrict__ srcW,
                                                const float* __restrict__ dinv,
                                                const float* __restrict__ bias,
                                                const float* __restrict__ Wfc,
                                                const float* __restrict__ bfc,
                                                float* __restrict__ out, int n) {
    int node = blockIdx.x * 4 + (threadIdx.x >> 6);
    if (node >= n) return;
    int lane = threadIdx.x & 63;
    int fs = lane & 15, jg = lane >> 4;
    float di = dinv[node];
    float acc[8];
    agg_core(hin, ptr, srcW, node, fs, jg, di, acc);
    // all 64 lanes hold full sums for features fs*8..fs*8+7
    const float4* b4 = (const float4*)bias;
    float4 bb0 = b4[fs * 2], bb1 = b4[fs * 2 + 1];
    float h[8];
    h[0] = fmaf(di, acc[0], bb0.x); h[1] = fmaf(di, acc[1], bb0.y);
    h[2] = fmaf(di, acc[2], bb0.z); h[3] = fmaf(di, acc[3], bb0.w);
    h[4] = fmaf(di, acc[4], bb1.x); h[5] = fmaf(di, acc[5], bb1.y);
    h[6] = fmaf(di, acc[6], bb1.z); h[7] = fmaf(di, acc[7], bb1.w);
    // FC: lane covers outputs c0=2*jg, c0+1 over its 8 features; Wfc 4KB L1-hot
    int c0 = jg * 2;
    float p0 = 0.f, p1 = 0.f;
#pragma unroll
    for (int k = 0; k < 8; k++) {
        const float* wr = Wfc + (size_t)(fs * 8 + k) * CDIM + c0;
        p0 = fmaf(h[k], wr[0], p0);
        p1 = fmaf(h[k], wr[1], p1);
    }
#pragma unroll
    for (int off = 1; off < 16; off <<= 1) {
        p0 += __shfl_xor(p0, off, 64);
        p1 += __shfl_xor(p1, off, 64);
    }
    if (fs == 0) {
        out[(size_t)node * CDIM + c0]     = p0 + bfc[c0];
        out[(size_t)node * CDIM + c0 + 1] = p1 + bfc[c0 + 1];
    }
}

extern "C" void kernel_launch(void* const* d_in, const int* in_sizes, int n_in,
                              void* d_out, int out_size, void* d_ws, size_t ws_size,
                              hipStream_t stream) {
    const float* x   = (const float*)d_in[0];
    const int*   ei  = (const int*)d_in[1];
    const float* W1  = (const float*)d_in[2];
    const float* b1  = (const float*)d_in[3];
    const float* W2  = (const float*)d_in[4];
    const float* b2  = (const float*)d_in[5];
    const float* Wfc = (const float*)d_in[6];
    const float* bfc = (const float*)d_in[7];
    float* out = (float*)d_out;

    const int N = in_sizes[0] / HDIM;   // 50000
    const int E = in_sizes[1] / 2;      // 800000
    const int B = (N + SCAN_CHUNK - 1) / SCAN_CHUNK;   // 13

    // workspace layout
    float*          bufF = (float*)d_ws;                                  // N*128 fp32
    __hip_bfloat16* bufH = (__hip_bfloat16*)(bufF + (size_t)N * HDIM);    // N*128 bf16
    float* dinv   = (float*)(bufH + (size_t)N * HDIM);  // N
    int*   cnt    = (int*)(dinv + N);                   // N      } zeroed together
    int*   status = cnt + N;                            // 16     }
    int*   ptr    = status + 16;                        // N+1
    int*   cursor = ptr + (N + 1);                      // N
    int2*  srcW   = (int2*)(((uintptr_t)(cursor + N) + 15) & ~(uintptr_t)15);  // E int2

    hipMemsetAsync(cnt, 0, (size_t)(N + 16) * sizeof(int), stream);
    k_hist<<<(E + 255) / 256, 256, 0, stream>>>(ei + E, cnt, E);
    k_scan<<<B, 256, 0, stream>>>(cnt, status, ptr, cursor, dinv, N, E);

    const int Gg = (N + 31) / 32;          // 1563 gemm blocks; 2*Gg=3126 >= 3125 scatter
    k_scatter_gemm<<<3 * Gg, 256, 0, stream>>>(ei, cursor, srcW, E, dinv, x, W1, bufH, N);

    k_agg<<<(N + 3) / 4, 256, 0, stream>>>(bufH, bufF, ptr, srcW, dinv, b1, N);
    k_gemm<<<Gg, 256, 0, stream>>>(bufF, W2, bufH, N);
    k_agg_fc<<<(N + 3) / 4, 256, 0, stream>>>(bufH, ptr, srcW, dinv, b2, Wfc, bfc, out, N);
}